// Round 5
// baseline (850.928 us; speedup 1.0000x reference)
//
#include <hip/hip_runtime.h>
#include <stdint.h>

using u16 = unsigned short;
typedef __attribute__((ext_vector_type(8))) short short8;   // 8 bf16 (4 VGPRs) MFMA A/B frag
typedef __attribute__((ext_vector_type(4))) float floatx4;  // MFMA C/D frag

__device__ __forceinline__ float b2f(u16 s) {
    union { unsigned u; float f; } x; x.u = ((unsigned)s) << 16; return x.f;
}
__device__ __forceinline__ u16 f2b(float f) {
    unsigned u = __float_as_uint(f);
    unsigned r = (u + 0x7fffu + ((u >> 16) & 1u)) >> 16;  // RNE
    return (u16)r;
}

// async global->LDS, 16B per lane; lds dst = wave-uniform base + lane*16
__device__ __forceinline__ void gl16(const u16* g, u16* l) {
    __builtin_amdgcn_global_load_lds((const __attribute__((address_space(1))) void*)g,
                                     (__attribute__((address_space(3))) void*)l,
                                     16, 0, 0);
}

// ---------------------------------------------------------------------------
// GroupNorm stats: one block per (b,g); mean/var over H*W*(C/G) = 65536 f32
// ---------------------------------------------------------------------------
__global__ __launch_bounds__(256) void gn_stats_k(const float* __restrict__ x,
                                                  float* __restrict__ stats) {
    int bg = blockIdx.x;               // 0..127
    int b = bg >> 5, g = bg & 31;
    const size_t base = (size_t)b * 4096 * 512 + g * 16;
    int t = threadIdx.x;
    float s = 0.f, ss = 0.f;
    for (int it = 0; it < 64; ++it) {
        int vi = it * 256 + t;         // 16384 float4 vectors
        int n = vi >> 2;               // token 0..4095
        int j = (vi & 3) * 4;          // channel-within-group 0,4,8,12
        float4 u = *(const float4*)(x + base + (size_t)n * 512 + j);
        s += u.x + u.y + u.z + u.w;
        ss += u.x * u.x + u.y * u.y + u.z * u.z + u.w * u.w;
    }
    for (int off = 32; off; off >>= 1) {
        s  += __shfl_down(s, off, 64);
        ss += __shfl_down(ss, off, 64);
    }
    __shared__ float rs[4], rss[4];
    int lane = t & 63, w = t >> 6;
    if (lane == 0) { rs[w] = s; rss[w] = ss; }
    __syncthreads();
    if (t == 0) {
        float S1 = rs[0] + rs[1] + rs[2] + rs[3];
        float S2 = rss[0] + rss[1] + rss[2] + rss[3];
        float mean = S1 * (1.f / 65536.f);
        float var  = S2 * (1.f / 65536.f) - mean * mean;
        stats[2 * bg]     = mean;
        stats[2 * bg + 1] = rsqrtf(var + 1e-6f);
    }
}

// ---------------------------------------------------------------------------
// GroupNorm apply: h(bf16) = (x - mean) * rstd * gamma + beta, 4 f32/thread
// ---------------------------------------------------------------------------
__global__ __launch_bounds__(256) void gn_apply_k(const float* __restrict__ x,
                                                  const float* __restrict__ gamma,
                                                  const float* __restrict__ beta,
                                                  const float* __restrict__ stats,
                                                  u16* __restrict__ h) {
    size_t v = (size_t)blockIdx.x * 256 + threadIdx.x;   // float4 index
    size_t e = v * 4;
    int c = (int)(e & 511);            // multiple of 4; never crosses 16-ch group
    int b = (int)(e >> 21);            // e / (4096*512)
    int g = c >> 4;
    float mean = stats[2 * (b * 32 + g)];
    float rstd = stats[2 * (b * 32 + g) + 1];
    float4 xv = *(const float4*)(x + e);
    float4 gv = *(const float4*)(gamma + c);
    float4 bv = *(const float4*)(beta + c);
    ushort4 o;
    o.x = f2b((xv.x - mean) * rstd * gv.x + bv.x);
    o.y = f2b((xv.y - mean) * rstd * gv.y + bv.y);
    o.z = f2b((xv.z - mean) * rstd * gv.z + bv.z);
    o.w = f2b((xv.w - mean) * rstd * gv.w + bv.w);
    *(ushort4*)(h + e) = o;
}

// ---------------------------------------------------------------------------
// 512x512 fp32 -> bf16 transposed copy (for weight matrices)
// ---------------------------------------------------------------------------
__global__ __launch_bounds__(256) void transpose_f2b(const float* __restrict__ src,
                                                     u16* __restrict__ dst) {
    __shared__ float tile[32][33];
    int tx = threadIdx.x, ty = threadIdx.y;   // (32,8)
    int r0 = blockIdx.x * 32, c0 = blockIdx.y * 32;
#pragma unroll
    for (int i = 0; i < 4; ++i)
        tile[ty + i * 8][tx] = src[(size_t)(r0 + ty + i * 8) * 512 + c0 + tx];
    __syncthreads();
#pragma unroll
    for (int i = 0; i < 4; ++i)
        dst[(size_t)(c0 + ty + i * 8) * 512 + r0 + tx] = f2b(tile[tx][ty + i * 8]);
}

// ---------------------------------------------------------------------------
// bf16 -> bf16 transposed copy (V tiles), batched via blockIdx.z
// ---------------------------------------------------------------------------
__global__ __launch_bounds__(256) void transpose_b2b(const u16* __restrict__ src,
                                                     u16* __restrict__ dst,
                                                     int src_ld, int dst_ld,
                                                     long long sSrc, long long sDst) {
    __shared__ u16 tile[32][33];
    src += (size_t)blockIdx.z * sSrc;
    dst += (size_t)blockIdx.z * sDst;
    int tx = threadIdx.x, ty = threadIdx.y;   // (32,8)
    int r0 = blockIdx.x * 32, c0 = blockIdx.y * 32;
#pragma unroll
    for (int i = 0; i < 4; ++i)
        tile[ty + i * 8][tx] = src[(size_t)(r0 + ty + i * 8) * src_ld + c0 + tx];
    __syncthreads();
#pragma unroll
    for (int i = 0; i < 4; ++i)
        dst[(size_t)(c0 + ty + i * 8) * dst_ld + r0 + tx] = tile[tx][ty + i * 8];
}

__global__ __launch_bounds__(256) void concat_bias_f(const float* __restrict__ bq,
                                                     const float* __restrict__ bk,
                                                     const float* __restrict__ bv,
                                                     float* __restrict__ dst) {
    int i = blockIdx.x * 256 + threadIdx.x;   // 1536
    const float* src = (i < 512) ? bq : (i < 1024) ? bk : bv;
    dst[i] = src[i & 511];
}

// ---------------------------------------------------------------------------
// GEMM, C = scale*(A @ B^T) + bias (+resid), bf16 operands, fp32 accum.
// global_load_lds(16B) staging. Output bf16 to C or fp32 to Cf. 128x128 tile.
// ---------------------------------------------------------------------------
__global__ __launch_bounds__(256) void gemm_bt(const u16* __restrict__ A, int lda,
                                               const u16* __restrict__ B, int ldb,
                                               u16* __restrict__ C, float* __restrict__ Cf,
                                               int ldc,
                                               const float* __restrict__ bias,
                                               const float* __restrict__ resid,
                                               int K, float scale) {
    __shared__ u16 As[128 * 32];
    __shared__ u16 Bs[128 * 32];
    const int t = threadIdx.x;
    const int lane = t & 63, w = t >> 6;
    const int wm = (w >> 1) * 64, wn = (w & 1) * 64;
    const int r = lane & 15, q = lane >> 4;
    const int m0 = blockIdx.x * 128;
    const int n0 = blockIdx.y * 128;

    floatx4 acc[4][4];
#pragma unroll
    for (int mi = 0; mi < 4; ++mi)
#pragma unroll
        for (int ni = 0; ni < 4; ++ni) acc[mi][ni] = (floatx4){0.f, 0.f, 0.f, 0.f};

    const int srow = lane >> 2;
    const int scol = (lane & 3) * 8;
    const u16* gA = A + (size_t)(m0 + w * 32 + srow) * lda + scol;
    const u16* gB = B + (size_t)(n0 + w * 32 + srow) * ldb + scol;
    u16* lA = As + w * 1024;
    u16* lB = Bs + w * 1024;

    for (int k0 = 0; k0 < K; k0 += 32) {
        __syncthreads();
        gl16(gA,                     lA);
        gl16(gA + (size_t)16 * lda,  lA + 512);
        gl16(gB,                     lB);
        gl16(gB + (size_t)16 * ldb,  lB + 512);
        gA += 32; gB += 32;
        __syncthreads();
        short8 af[4], bfr[4];
#pragma unroll
        for (int mi = 0; mi < 4; ++mi)
            af[mi] = *(const short8*)(As + (wm + mi * 16 + r) * 32 + q * 8);
#pragma unroll
        for (int ni = 0; ni < 4; ++ni)
            bfr[ni] = *(const short8*)(Bs + (wn + ni * 16 + r) * 32 + q * 8);
#pragma unroll
        for (int mi = 0; mi < 4; ++mi)
#pragma unroll
            for (int ni = 0; ni < 4; ++ni)
                acc[mi][ni] = __builtin_amdgcn_mfma_f32_16x16x32_bf16(af[mi], bfr[ni],
                                                                      acc[mi][ni], 0, 0, 0);
    }

#pragma unroll
    for (int ni = 0; ni < 4; ++ni) {
        int col = n0 + wn + ni * 16 + r;
        float bv = bias ? bias[col] : 0.f;
#pragma unroll
        for (int mi = 0; mi < 4; ++mi) {
            int rowb = m0 + wm + mi * 16 + q * 4;
#pragma unroll
            for (int i = 0; i < 4; ++i) {
                size_t off = (size_t)(rowb + i) * ldc + col;
                float v = acc[mi][ni][i] * scale + bv;
                if (resid) v += resid[off];
                if (Cf) Cf[off] = v;
                else    C[off] = f2b(v);
            }
        }
    }
}

// ---------------------------------------------------------------------------
// Fused flash attention: ao = softmax(Q K^T / sqrt(512)) V, per batch.
// Grid (128 Q-tiles, 4 batches), 128 thr (2 waves) -> 512 blocks, 2 per CU
// (72 KB LDS). Wave owns 16 Q-rows; Q pre-scaled by 512^-0.5*log2e in regs.
// S^T = K @ Q^T; per-lane online softmax (lane owns one Q-row column);
// P via XOR-swizzled wave-private LDS; O accum 128 f32/lane.
// K/V staged in 16 KB double-buffered chunks, one chunk of lookahead.
// ---------------------------------------------------------------------------
#define FLASH_SMEM 73728
__global__ __launch_bounds__(128, 2) void flash_k(const u16* __restrict__ qkv,
                                                  const u16* __restrict__ vt,
                                                  u16* __restrict__ ao) {
    extern __shared__ u16 smem[];
    u16* Ks = smem;                 // 2 bufs x 8192 elems: [2 sub][128 key][32 ch]
    u16* Vs = smem + 16384;         // 2 bufs x 8192 elems: [256 ch][32 key]
    u16* Pl = smem + 32768;         // 2 waves x 2048 elems: [16 row][128 key] swizzled
    const int t = threadIdx.x;
    const int lane = t & 63, w = t >> 6;
    const int r = lane & 15, q = lane >> 4;
    const int b = blockIdx.y, qt = blockIdx.x;
    const u16* qb = qkv + (size_t)b * 4096 * 1536;
    const u16* kb = qb + 512;
    const u16* vb = vt + (size_t)b * 512 * 4096;
    u16* aob = ao + (size_t)b * 4096 * 512;

    // stage K chunk: [128 key][64 ch at g*64] -> Ks[buf], layout [2 sub][128 key][32 ch]
    auto stageK = [&](int buf, int kt, int g) {
#pragma unroll
        for (int j = 0; j < 8; ++j) {
            int u = (w * 8 + j) * 512 + lane * 8;
            int key = (u >> 5) & 127;
            int sub = u >> 12;
            int c = u & 31;
            gl16(kb + (size_t)(kt * 128 + key) * 1536 + g * 64 + sub * 32 + c,
                 Ks + buf * 8192 + u);
        }
    };
    // stage V chunk: [256 ch at half*256][32 key at k*32] -> Vs[buf], [256 ch][32 key]
    auto stageV = [&](int buf, int kt, int k, int half) {
#pragma unroll
        for (int j = 0; j < 8; ++j) {
            int u = (w * 8 + j) * 512 + lane * 8;
            int ch = u >> 5;
            int kk = u & 31;
            gl16(vb + (size_t)(half * 256 + ch) * 4096 + kt * 128 + k * 32 + kk,
                 Vs + buf * 8192 + u);
        }
    };

    stageK(0, 0, 0);

    // Q fragments pre-scaled by 512^-0.5 * log2(e): Qreg[kit] = Q[qrow][kit*32+q*8..+7]
    const float sc2 = 0.06375872f;
    const int qrow = qt * 32 + w * 16 + r;
    short8 Qreg[16];
#pragma unroll
    for (int kit = 0; kit < 16; ++kit) {
        short8 qv = *(const short8*)(qb + (size_t)qrow * 1536 + kit * 32 + q * 8);
#pragma unroll
        for (int e = 0; e < 8; ++e)
            qv[e] = (short)f2b(b2f((u16)qv[e]) * sc2);
        Qreg[kit] = qv;
    }

    floatx4 acc_o[32];
#pragma unroll
    for (int ni = 0; ni < 32; ++ni) acc_o[ni] = (floatx4){0.f, 0.f, 0.f, 0.f};
    float m_run = -3.0e38f, l_run = 0.f;
    u16* pw = Pl + w * 2048;

    for (int kt = 0; kt < 32; ++kt) {
        // ----- S^T = K_tile @ Q^T (pre-scaled): acc_s[mi][i] = log2-score
        floatx4 acc_s[8];
#pragma unroll
        for (int mi = 0; mi < 8; ++mi) acc_s[mi] = (floatx4){0.f, 0.f, 0.f, 0.f};
#pragma unroll
        for (int g = 0; g < 8; ++g) {
            __syncthreads();                       // drains stage issued last phase
            if (g < 7) stageK((g + 1) & 1, kt, g + 1);
            else       stageV(0, kt, 0, 0);
            const u16* kbase = Ks + (g & 1) * 8192;
#pragma unroll
            for (int s = 0; s < 2; ++s) {
                const u16* sbase = kbase + s * 4096;
#pragma unroll
                for (int mi = 0; mi < 8; ++mi) {
                    short8 af = *(const short8*)(sbase + (mi * 16 + r) * 32 + q * 8);
                    acc_s[mi] = __builtin_amdgcn_mfma_f32_16x16x32_bf16(
                        af, Qreg[g * 2 + s], acc_s[mi], 0, 0, 0);
                }
            }
        }
        // ----- online softmax (no barriers; lane owns Q-row qrow's column)
        float m_t = -3.0e38f;
#pragma unroll
        for (int mi = 0; mi < 8; ++mi)
#pragma unroll
            for (int i = 0; i < 4; ++i) m_t = fmaxf(m_t, acc_s[mi][i]);
        m_t = fmaxf(m_t, __shfl_xor(m_t, 16, 64));
        m_t = fmaxf(m_t, __shfl_xor(m_t, 32, 64));
        float m_new = fmaxf(m_run, m_t);
        unsigned long long upd = __ballot(m_t > m_run);
        float p[32];
        float rs = 0.f;
#pragma unroll
        for (int mi = 0; mi < 8; ++mi)
#pragma unroll
            for (int i = 0; i < 4; ++i) {
                float pv = __builtin_amdgcn_exp2f(acc_s[mi][i] - m_new);
                p[mi * 4 + i] = pv;
                rs += pv;
            }
        rs += __shfl_xor(rs, 16, 64);
        rs += __shfl_xor(rs, 32, 64);
        if (upd) {
            float alpha = __builtin_amdgcn_exp2f(m_run - m_new);
            l_run *= alpha;
            float a0 = __shfl(alpha, q * 4 + 0, 64);
            float a1 = __shfl(alpha, q * 4 + 1, 64);
            float a2 = __shfl(alpha, q * 4 + 2, 64);
            float a3 = __shfl(alpha, q * 4 + 3, 64);
#pragma unroll
            for (int ni = 0; ni < 32; ++ni) {
                acc_o[ni][0] *= a0; acc_o[ni][1] *= a1;
                acc_o[ni][2] *= a2; acc_o[ni][3] *= a3;
            }
        }
        l_run += rs;
        m_run = m_new;
        // ----- pack P -> bf16, wave-private LDS [row r][128 keys], XOR swizzle
#pragma unroll
        for (int mi = 0; mi < 8; ++mi) {
            uint2 vv;
            vv.x = (unsigned)f2b(p[mi * 4 + 0]) | ((unsigned)f2b(p[mi * 4 + 1]) << 16);
            vv.y = (unsigned)f2b(p[mi * 4 + 2]) | ((unsigned)f2b(p[mi * 4 + 3]) << 16);
            *(uint2*)(pw + r * 128 + (((2 * mi + (q >> 1)) ^ (r & 7)) * 8) + (q & 1) * 4) = vv;
        }
        // ----- PV: 8 chunks (k = key-quad, half = channel half)
        short8 ap;
#pragma unroll
        for (int p8 = 0; p8 < 8; ++p8) {
            __syncthreads();
            if (p8 < 7)       stageV((p8 + 1) & 1, kt, (p8 + 1) >> 1, (p8 + 1) & 1);
            else if (kt < 31) stageK(0, kt + 1, 0);
            const int k = p8 >> 1, half = p8 & 1;
            if (half == 0)
                ap = *(const short8*)(pw + r * 128 + (((k * 4 + q) ^ (r & 7)) * 8));
            const u16* vbase = Vs + (p8 & 1) * 8192;
#pragma unroll
            for (int nl = 0; nl < 16; ++nl) {
                short8 bf = *(const short8*)(vbase + (nl * 16 + r) * 32 + q * 8);
                acc_o[half * 16 + nl] = __builtin_amdgcn_mfma_f32_16x16x32_bf16(
                    ap, bf, acc_o[half * 16 + nl], 0, 0, 0);
            }
        }
    }
    // ----- epilogue: O row rowb+i, col ni*16+r; divide by l (shfl'd)
    float inv0 = 1.f / __shfl(l_run, q * 4 + 0, 64);
    float inv1 = 1.f / __shfl(l_run, q * 4 + 1, 64);
    float inv2 = 1.f / __shfl(l_run, q * 4 + 2, 64);
    float inv3 = 1.f / __shfl(l_run, q * 4 + 3, 64);
    const int rowb = qt * 32 + w * 16 + q * 4;
#pragma unroll
    for (int ni = 0; ni < 32; ++ni) {
        int col = ni * 16 + r;
        aob[(size_t)(rowb + 0) * 512 + col] = f2b(acc_o[ni][0] * inv0);
        aob[(size_t)(rowb + 1) * 512 + col] = f2b(acc_o[ni][1] * inv1);
        aob[(size_t)(rowb + 2) * 512 + col] = f2b(acc_o[ni][2] * inv2);
        aob[(size_t)(rowb + 3) * 512 + col] = f2b(acc_o[ni][3] * inv3);
    }
}

// ---------------------------------------------------------------------------
extern "C" void kernel_launch(void* const* d_in, const int* in_sizes, int n_in,
                              void* d_out, int out_size, void* d_ws, size_t ws_size,
                              hipStream_t stream) {
    const float* x     = (const float*)d_in[0];
    const float* gamma = (const float*)d_in[1];
    const float* beta  = (const float*)d_in[2];
    const float* Wq    = (const float*)d_in[3];
    const float* bq    = (const float*)d_in[4];
    const float* Wk    = (const float*)d_in[5];
    const float* bk    = (const float*)d_in[6];
    const float* Wv    = (const float*)d_in[7];
    const float* bv    = (const float*)d_in[8];
    const float* Wo    = (const float*)d_in[9];
    const float* bo    = (const float*)d_in[10];
    float* out = (float*)d_out;

    // B=4, N=4096, C=512, G=32 — ws layout (no S needed)
    char* ws = (char*)d_ws;
    float* stats  = (float*)(ws);                        // 128*2 f32
    float* bqkv   = (float*)(ws + 4096);                 // 1536 f32
    u16*   wqkv_t = (u16*)(ws + 16384);                  // [1536,512]
    u16*   wo_t   = wqkv_t + (size_t)1536 * 512;
    u16*   h      = wo_t + (size_t)512 * 512;            // [16384,512] (aliased as ao)
    u16*   qkv    = h   + (size_t)16384 * 512;           // [16384,1536]
    u16*   vt     = qkv + (size_t)16384 * 1536;          // [4][512][4096]
    u16*   ao     = h;                                   // h dead after QKV GEMM

    const long long sQKV = (long long)4096 * 1536;
    const long long sVT  = (long long)512 * 4096;

    dim3 tblk(32, 8, 1);
    transpose_f2b<<<dim3(16, 16, 1), tblk, 0, stream>>>(Wq, wqkv_t);
    transpose_f2b<<<dim3(16, 16, 1), tblk, 0, stream>>>(Wk, wqkv_t + 512 * 512);
    transpose_f2b<<<dim3(16, 16, 1), tblk, 0, stream>>>(Wv, wqkv_t + 1024 * 512);
    transpose_f2b<<<dim3(16, 16, 1), tblk, 0, stream>>>(Wo, wo_t);
    concat_bias_f<<<6, 256, 0, stream>>>(bq, bk, bv, bqkv);

    gn_stats_k<<<128, 256, 0, stream>>>(x, stats);
    gn_apply_k<<<8192, 256, 0, stream>>>(x, gamma, beta, stats, h);

    // QKV: [16384,512] @ [512,1536] -> qkv (+bias)
    gemm_bt<<<dim3(128, 12, 1), 256, 0, stream>>>(h, 512, wqkv_t, 512,
                                                  qkv, nullptr, 1536, bqkv, nullptr,
                                                  512, 1.0f);
    // v -> vt[b][c][n]
    transpose_b2b<<<dim3(128, 16, 4), tblk, 0, stream>>>(qkv + 1024, vt, 1536, 4096,
                                                         sQKV, sVT);
    // fused attention -> ao (512 blocks, 2 per CU)
    hipFuncSetAttribute((const void*)flash_k,
                        hipFuncAttributeMaxDynamicSharedMemorySize, FLASH_SMEM);
    flash_k<<<dim3(128, 4, 1), 128, FLASH_SMEM, stream>>>(qkv, vt, ao);

    // out = ao @ Wo + bo + x   (fp32 output + bias + residual)
    gemm_bt<<<dim3(128, 4, 1), 256, 0, stream>>>(ao, 512, wo_t, 512,
                                                 nullptr, out, 512, bo, x,
                                                 512, 1.0f);
}

// Round 6
// 694.036 us; speedup vs baseline: 1.2261x; 1.2261x over previous
//
#include <hip/hip_runtime.h>
#include <stdint.h>

using u16 = unsigned short;
typedef __attribute__((ext_vector_type(8))) short short8;   // 8 bf16 (4 VGPRs) MFMA A/B frag
typedef __attribute__((ext_vector_type(4))) float floatx4;  // MFMA C/D frag

__device__ __forceinline__ float b2f(u16 s) {
    union { unsigned u; float f; } x; x.u = ((unsigned)s) << 16; return x.f;
}
__device__ __forceinline__ u16 f2b(float f) {
    unsigned u = __float_as_uint(f);
    unsigned r = (u + 0x7fffu + ((u >> 16) & 1u)) >> 16;  // RNE
    return (u16)r;
}

// async global->LDS, 16B per lane; lds dst = wave-uniform base + lane*16
__device__ __forceinline__ void gl16(const u16* g, u16* l) {
    __builtin_amdgcn_global_load_lds((const __attribute__((address_space(1))) void*)g,
                                     (__attribute__((address_space(3))) void*)l,
                                     16, 0, 0);
}

// ---------------------------------------------------------------------------
// GroupNorm stats: one block per (b,g); mean/var over H*W*(C/G) = 65536 f32
// ---------------------------------------------------------------------------
__global__ __launch_bounds__(256) void gn_stats_k(const float* __restrict__ x,
                                                  float* __restrict__ stats) {
    int bg = blockIdx.x;               // 0..127
    int b = bg >> 5, g = bg & 31;
    const size_t base = (size_t)b * 4096 * 512 + g * 16;
    int t = threadIdx.x;
    float s = 0.f, ss = 0.f;
    for (int it = 0; it < 64; ++it) {
        int vi = it * 256 + t;         // 16384 float4 vectors
        int n = vi >> 2;               // token 0..4095
        int j = (vi & 3) * 4;          // channel-within-group 0,4,8,12
        float4 u = *(const float4*)(x + base + (size_t)n * 512 + j);
        s += u.x + u.y + u.z + u.w;
        ss += u.x * u.x + u.y * u.y + u.z * u.z + u.w * u.w;
    }
    for (int off = 32; off; off >>= 1) {
        s  += __shfl_down(s, off, 64);
        ss += __shfl_down(ss, off, 64);
    }
    __shared__ float rs[4], rss[4];
    int lane = t & 63, w = t >> 6;
    if (lane == 0) { rs[w] = s; rss[w] = ss; }
    __syncthreads();
    if (t == 0) {
        float S1 = rs[0] + rs[1] + rs[2] + rs[3];
        float S2 = rss[0] + rss[1] + rss[2] + rss[3];
        float mean = S1 * (1.f / 65536.f);
        float var  = S2 * (1.f / 65536.f) - mean * mean;
        stats[2 * bg]     = mean;
        stats[2 * bg + 1] = rsqrtf(var + 1e-6f);
    }
}

// ---------------------------------------------------------------------------
// GroupNorm apply: h(bf16) = (x - mean) * rstd * gamma + beta, 4 f32/thread
// ---------------------------------------------------------------------------
__global__ __launch_bounds__(256) void gn_apply_k(const float* __restrict__ x,
                                                  const float* __restrict__ gamma,
                                                  const float* __restrict__ beta,
                                                  const float* __restrict__ stats,
                                                  u16* __restrict__ h) {
    size_t v = (size_t)blockIdx.x * 256 + threadIdx.x;   // float4 index
    size_t e = v * 4;
    int c = (int)(e & 511);            // multiple of 4; never crosses 16-ch group
    int b = (int)(e >> 21);            // e / (4096*512)
    int g = c >> 4;
    float mean = stats[2 * (b * 32 + g)];
    float rstd = stats[2 * (b * 32 + g) + 1];
    float4 xv = *(const float4*)(x + e);
    float4 gv = *(const float4*)(gamma + c);
    float4 bv = *(const float4*)(beta + c);
    ushort4 o;
    o.x = f2b((xv.x - mean) * rstd * gv.x + bv.x);
    o.y = f2b((xv.y - mean) * rstd * gv.y + bv.y);
    o.z = f2b((xv.z - mean) * rstd * gv.z + bv.z);
    o.w = f2b((xv.w - mean) * rstd * gv.w + bv.w);
    *(ushort4*)(h + e) = o;
}

// ---------------------------------------------------------------------------
// 512x512 fp32 -> bf16 transposed copy (for weight matrices)
// ---------------------------------------------------------------------------
__global__ __launch_bounds__(256) void transpose_f2b(const float* __restrict__ src,
                                                     u16* __restrict__ dst) {
    __shared__ float tile[32][33];
    int tx = threadIdx.x, ty = threadIdx.y;   // (32,8)
    int r0 = blockIdx.x * 32, c0 = blockIdx.y * 32;
#pragma unroll
    for (int i = 0; i < 4; ++i)
        tile[ty + i * 8][tx] = src[(size_t)(r0 + ty + i * 8) * 512 + c0 + tx];
    __syncthreads();
#pragma unroll
    for (int i = 0; i < 4; ++i)
        dst[(size_t)(c0 + ty + i * 8) * 512 + r0 + tx] = f2b(tile[tx][ty + i * 8]);
}

// ---------------------------------------------------------------------------
// bf16 -> bf16 transposed copy (V tiles), batched via blockIdx.z
// ---------------------------------------------------------------------------
__global__ __launch_bounds__(256) void transpose_b2b(const u16* __restrict__ src,
                                                     u16* __restrict__ dst,
                                                     int src_ld, int dst_ld,
                                                     long long sSrc, long long sDst) {
    __shared__ u16 tile[32][33];
    src += (size_t)blockIdx.z * sSrc;
    dst += (size_t)blockIdx.z * sDst;
    int tx = threadIdx.x, ty = threadIdx.y;   // (32,8)
    int r0 = blockIdx.x * 32, c0 = blockIdx.y * 32;
#pragma unroll
    for (int i = 0; i < 4; ++i)
        tile[ty + i * 8][tx] = src[(size_t)(r0 + ty + i * 8) * src_ld + c0 + tx];
    __syncthreads();
#pragma unroll
    for (int i = 0; i < 4; ++i)
        dst[(size_t)(c0 + ty + i * 8) * dst_ld + r0 + tx] = tile[tx][ty + i * 8];
}

__global__ __launch_bounds__(256) void concat_bias_f(const float* __restrict__ bq,
                                                     const float* __restrict__ bk,
                                                     const float* __restrict__ bv,
                                                     float* __restrict__ dst) {
    int i = blockIdx.x * 256 + threadIdx.x;   // 1536
    const float* src = (i < 512) ? bq : (i < 1024) ? bk : bv;
    dst[i] = src[i & 511];
}

// ---------------------------------------------------------------------------
// GEMM, C = scale*(A @ B^T) + bias (+resid), bf16 operands, fp32 accum.
// global_load_lds(16B) staging. Output bf16 to C or fp32 to Cf. 128x128 tile.
// ---------------------------------------------------------------------------
__global__ __launch_bounds__(256) void gemm_bt(const u16* __restrict__ A, int lda,
                                               const u16* __restrict__ B, int ldb,
                                               u16* __restrict__ C, float* __restrict__ Cf,
                                               int ldc,
                                               const float* __restrict__ bias,
                                               const float* __restrict__ resid,
                                               int K, float scale) {
    __shared__ u16 As[128 * 32];
    __shared__ u16 Bs[128 * 32];
    const int t = threadIdx.x;
    const int lane = t & 63, w = t >> 6;
    const int wm = (w >> 1) * 64, wn = (w & 1) * 64;
    const int r = lane & 15, q = lane >> 4;
    const int m0 = blockIdx.x * 128;
    const int n0 = blockIdx.y * 128;

    floatx4 acc[4][4];
#pragma unroll
    for (int mi = 0; mi < 4; ++mi)
#pragma unroll
        for (int ni = 0; ni < 4; ++ni) acc[mi][ni] = (floatx4){0.f, 0.f, 0.f, 0.f};

    const int srow = lane >> 2;
    const int scol = (lane & 3) * 8;
    const u16* gA = A + (size_t)(m0 + w * 32 + srow) * lda + scol;
    const u16* gB = B + (size_t)(n0 + w * 32 + srow) * ldb + scol;
    u16* lA = As + w * 1024;
    u16* lB = Bs + w * 1024;

    for (int k0 = 0; k0 < K; k0 += 32) {
        __syncthreads();
        gl16(gA,                     lA);
        gl16(gA + (size_t)16 * lda,  lA + 512);
        gl16(gB,                     lB);
        gl16(gB + (size_t)16 * ldb,  lB + 512);
        gA += 32; gB += 32;
        __syncthreads();
        short8 af[4], bfr[4];
#pragma unroll
        for (int mi = 0; mi < 4; ++mi)
            af[mi] = *(const short8*)(As + (wm + mi * 16 + r) * 32 + q * 8);
#pragma unroll
        for (int ni = 0; ni < 4; ++ni)
            bfr[ni] = *(const short8*)(Bs + (wn + ni * 16 + r) * 32 + q * 8);
#pragma unroll
        for (int mi = 0; mi < 4; ++mi)
#pragma unroll
            for (int ni = 0; ni < 4; ++ni)
                acc[mi][ni] = __builtin_amdgcn_mfma_f32_16x16x32_bf16(af[mi], bfr[ni],
                                                                      acc[mi][ni], 0, 0, 0);
    }

#pragma unroll
    for (int ni = 0; ni < 4; ++ni) {
        int col = n0 + wn + ni * 16 + r;
        float bv = bias ? bias[col] : 0.f;
#pragma unroll
        for (int mi = 0; mi < 4; ++mi) {
            int rowb = m0 + wm + mi * 16 + q * 4;
#pragma unroll
            for (int i = 0; i < 4; ++i) {
                size_t off = (size_t)(rowb + i) * ldc + col;
                float v = acc[mi][ni][i] * scale + bv;
                if (resid) v += resid[off];
                if (Cf) Cf[off] = v;
                else    C[off] = f2b(v);
            }
        }
    }
}

// ---------------------------------------------------------------------------
// flash3: ao = softmax(Q K^T / sqrt(512)) V. Block = 32 Q-rows, 4 waves,
// grid (128, 4) = 512 blocks, 2 blocks/CU (73 KB LDS, <=256 unified regs).
// Q in registers (pre-scaled by 512^-0.5*log2e). Waves split KEYS in the
// QK^T phase (wave w: keys w*32..+31 of each 128-key tile) and split
// CHANNELS in the PV phase (wave w: ch w*64 within each 256-ch half).
// Cross-wave online softmax via 2 small LDS barriers per key-tile.
// Each K-frag read feeds 2 MFMA (2 row-tiles); P-frag reused 8x.
// ---------------------------------------------------------------------------
#define FLASH_SMEM 74752
__global__ __launch_bounds__(256, 2) void flash_k(const u16* __restrict__ qkv,
                                                  const u16* __restrict__ vt,
                                                  u16* __restrict__ ao) {
    extern __shared__ u16 smem[];
    u16* Ks = smem;                        // 2 bufs x [2 sub][128 key][32 ch] (2 x 16 KB)
    u16* Vs = smem + 16384;                // 2 bufs x [256 ch][32 key]        (2 x 16 KB)
    u16* Pl = smem + 32768;                // [32 row][128 key] swizzled        (8 KB)
    float* smx = (float*)(smem + 36864);   // [4 wave][32 row] max partials
    float* sms = smx + 128;                // [4 wave][32 row] sum partials
    const int t = threadIdx.x;
    const int lane = t & 63, w = t >> 6;
    const int r = lane & 15, q = lane >> 4;
    const int b = blockIdx.y, qt = blockIdx.x;   // qt: 0..127 (32 rows each)
    const u16* qb = qkv + (size_t)b * 4096 * 1536;
    const u16* kb = qb + 512;
    const u16* vb = vt + (size_t)b * 512 * 4096;
    u16* aob = ao + (size_t)b * 4096 * 512;

    // stage K chunk: [128 key][64 ch at g*64] -> Ks[buf] as [2 sub32][128 key][32 ch]
    auto stageK = [&](int buf, int kt, int g) {
#pragma unroll
        for (int j = 0; j < 4; ++j) {
            int i = w * 4 + j;               // 16 slices x 512 elems (1 KB each)
            int sub = i >> 3;
            int key = (i & 7) * 16 + (lane >> 2);
            int c = (lane & 3) * 8;
            gl16(kb + (size_t)(kt * 128 + key) * 1536 + g * 64 + sub * 32 + c,
                 Ks + buf * 8192 + i * 512 + lane * 8);
        }
    };
    // stage V chunk: [256 ch at h*256][32 key at c2*32] -> Vs[buf] as [256 ch][32 key]
    auto stageV = [&](int buf, int kt, int ph) {
        int c2 = ph >> 1, h = ph & 1;
#pragma unroll
        for (int j = 0; j < 4; ++j) {
            int i = w * 4 + j;               // slice = 16 ch x 32 key
            int ch = i * 16 + (lane >> 2);
            int key = (lane & 3) * 8;
            gl16(vb + (size_t)(h * 256 + ch) * 4096 + kt * 128 + c2 * 32 + key,
                 Vs + buf * 8192 + i * 512 + lane * 8);
        }
    };

    stageK(0, 0, 0);

    // Q in regs, pre-scaled: Qreg[rt][ks] = Q[qt*32+rt*16+r][ks*32+q*8..+7] * sc2
    const float sc2 = 0.06375872f;           // 512^-0.5 * log2(e)
    short8 Qreg[2][16];
#pragma unroll
    for (int rt = 0; rt < 2; ++rt)
#pragma unroll
        for (int ks = 0; ks < 16; ++ks) {
            short8 qv = *(const short8*)(qb + (size_t)(qt * 32 + rt * 16 + r) * 1536
                                         + ks * 32 + q * 8);
#pragma unroll
            for (int e = 0; e < 8; ++e)
                qv[e] = (short)f2b(b2f((u16)qv[e]) * sc2);
            Qreg[rt][ks] = qv;
        }

    floatx4 acc_o[2][8];                     // [rt][h*4+ct]: rows rt*16+q*4+i, ch h*256+w*64+ct*16+r
#pragma unroll
    for (int rt = 0; rt < 2; ++rt)
#pragma unroll
        for (int ni = 0; ni < 8; ++ni) acc_o[rt][ni] = (floatx4){0.f, 0.f, 0.f, 0.f};
    float m_run[2] = {-3.0e38f, -3.0e38f}, l_run[2] = {0.f, 0.f};

    for (int kt = 0; kt < 32; ++kt) {
        // ---- S^T phase: acc_s[kt2][rt][i] = S[key=w*32+kt2*16+q*4+i][row=rt*16+r]
        floatx4 acc_s[2][2];
#pragma unroll
        for (int kt2 = 0; kt2 < 2; ++kt2)
#pragma unroll
            for (int rt = 0; rt < 2; ++rt) acc_s[kt2][rt] = (floatx4){0.f, 0.f, 0.f, 0.f};
#pragma unroll
        for (int g = 0; g < 8; ++g) {
            __syncthreads();                 // drains stage issued last phase
            if (g < 7) stageK((g + 1) & 1, kt, g + 1);
            else       stageV(0, kt, 0);
            const u16* kbase = Ks + (g & 1) * 8192;
#pragma unroll
            for (int s = 0; s < 2; ++s) {
#pragma unroll
                for (int kt2 = 0; kt2 < 2; ++kt2) {
                    short8 af = *(const short8*)(kbase + s * 4096
                                                 + (w * 32 + kt2 * 16 + r) * 32 + q * 8);
#pragma unroll
                    for (int rt = 0; rt < 2; ++rt)
                        acc_s[kt2][rt] = __builtin_amdgcn_mfma_f32_16x16x32_bf16(
                            af, Qreg[rt][g * 2 + s], acc_s[kt2][rt], 0, 0, 0);
                }
            }
        }
        // ---- softmax part 1: wave-local per-row max over its 32 keys
        float mt[2];
#pragma unroll
        for (int rt = 0; rt < 2; ++rt) {
            float m = -3.0e38f;
#pragma unroll
            for (int kt2 = 0; kt2 < 2; ++kt2)
#pragma unroll
                for (int i = 0; i < 4; ++i) m = fmaxf(m, acc_s[kt2][rt][i]);
            m = fmaxf(m, __shfl_xor(m, 16, 64));
            m = fmaxf(m, __shfl_xor(m, 32, 64));
            mt[rt] = m;
        }
        if (q == 0) { smx[w * 32 + r] = mt[0]; smx[w * 32 + 16 + r] = mt[1]; }
        __syncthreads();                     // (A) partials visible; V chunk 0 drained
        float mnew[2], rsum[2];
#pragma unroll
        for (int rt = 0; rt < 2; ++rt) {
            float m = fmaxf(fmaxf(smx[rt * 16 + r], smx[32 + rt * 16 + r]),
                            fmaxf(smx[64 + rt * 16 + r], smx[96 + rt * 16 + r]));
            mnew[rt] = fmaxf(m_run[rt], m);
            float rs = 0.f;
#pragma unroll
            for (int kt2 = 0; kt2 < 2; ++kt2)
#pragma unroll
                for (int i = 0; i < 4; ++i) {
                    float pv = __builtin_amdgcn_exp2f(acc_s[kt2][rt][i] - mnew[rt]);
                    acc_s[kt2][rt][i] = pv;
                    rs += pv;
                }
            rs += __shfl_xor(rs, 16, 64);
            rs += __shfl_xor(rs, 32, 64);
            rsum[rt] = rs;
        }
        if (q == 0) { sms[w * 32 + r] = rsum[0]; sms[w * 32 + 16 + r] = rsum[1]; }
        // ---- pack P (keys w*32+kt2*16+q*4..+3, row rt*16+r), XOR-swizzled 8-groups
#pragma unroll
        for (int rt = 0; rt < 2; ++rt)
#pragma unroll
            for (int kt2 = 0; kt2 < 2; ++kt2) {
                uint2 vv;
                vv.x = (unsigned)f2b(acc_s[kt2][rt][0]) | ((unsigned)f2b(acc_s[kt2][rt][1]) << 16);
                vv.y = (unsigned)f2b(acc_s[kt2][rt][2]) | ((unsigned)f2b(acc_s[kt2][rt][3]) << 16);
                int kg = w * 4 + kt2 * 2 + (q >> 1);
                *(uint2*)(Pl + (rt * 16 + r) * 128 + ((kg ^ (r & 7)) << 3) + (q & 1) * 4) = vv;
            }
        __syncthreads();                     // (B) P + sum partials visible
#pragma unroll
        for (int rt = 0; rt < 2; ++rt) {
            float rs_all = sms[rt * 16 + r] + sms[32 + rt * 16 + r]
                         + sms[64 + rt * 16 + r] + sms[96 + rt * 16 + r];
            float alpha = __builtin_amdgcn_exp2f(m_run[rt] - mnew[rt]);
            l_run[rt] = l_run[rt] * alpha + rs_all;
            m_run[rt] = mnew[rt];
            float a0 = __shfl(alpha, q * 4 + 0, 64);
            float a1 = __shfl(alpha, q * 4 + 1, 64);
            float a2 = __shfl(alpha, q * 4 + 2, 64);
            float a3 = __shfl(alpha, q * 4 + 3, 64);
#pragma unroll
            for (int ni = 0; ni < 8; ++ni) {
                acc_o[rt][ni][0] *= a0; acc_o[rt][ni][1] *= a1;
                acc_o[rt][ni][2] *= a2; acc_o[rt][ni][3] *= a3;
            }
        }
        // ---- PV: 8 phases (c2 = key-32-chunk, h = ch-half); P frag reused across h
        short8 ap[2];
#pragma unroll
        for (int ph = 0; ph < 8; ++ph) {
            if (ph) __syncthreads();
            if (ph < 7)       stageV((ph + 1) & 1, kt, ph + 1);
            else if (kt < 31) stageK(0, kt + 1, 0);
            const int c2 = ph >> 1, h = ph & 1;
            if (h == 0) {
#pragma unroll
                for (int rt = 0; rt < 2; ++rt)
                    ap[rt] = *(const short8*)(Pl + (rt * 16 + r) * 128
                                              + (((c2 * 4 + q) ^ (r & 7)) << 3));
            }
            const u16* vbase = Vs + (ph & 1) * 8192;
#pragma unroll
            for (int ct = 0; ct < 4; ++ct) {
                short8 bf = *(const short8*)(vbase + (w * 64 + ct * 16 + r) * 32 + q * 8);
#pragma unroll
                for (int rt = 0; rt < 2; ++rt)
                    acc_o[rt][h * 4 + ct] = __builtin_amdgcn_mfma_f32_16x16x32_bf16(
                        ap[rt], bf, acc_o[rt][h * 4 + ct], 0, 0, 0);
            }
        }
    }
    // ---- epilogue: row = qt*32 + rt*16 + q*4 + i, col = h*256 + w*64 + ct*16 + r
#pragma unroll
    for (int rt = 0; rt < 2; ++rt) {
        float inv0 = 1.f / __shfl(l_run[rt], q * 4 + 0, 64);
        float inv1 = 1.f / __shfl(l_run[rt], q * 4 + 1, 64);
        float inv2 = 1.f / __shfl(l_run[rt], q * 4 + 2, 64);
        float inv3 = 1.f / __shfl(l_run[rt], q * 4 + 3, 64);
        const int rowb = qt * 32 + rt * 16 + q * 4;
#pragma unroll
        for (int ni = 0; ni < 8; ++ni) {
            int col = (ni >> 2) * 256 + w * 64 + (ni & 3) * 16 + r;
            aob[(size_t)(rowb + 0) * 512 + col] = f2b(acc_o[rt][ni][0] * inv0);
            aob[(size_t)(rowb + 1) * 512 + col] = f2b(acc_o[rt][ni][1] * inv1);
            aob[(size_t)(rowb + 2) * 512 + col] = f2b(acc_o[rt][ni][2] * inv2);
            aob[(size_t)(rowb + 3) * 512 + col] = f2b(acc_o[rt][ni][3] * inv3);
        }
    }
}

// ---------------------------------------------------------------------------
extern "C" void kernel_launch(void* const* d_in, const int* in_sizes, int n_in,
                              void* d_out, int out_size, void* d_ws, size_t ws_size,
                              hipStream_t stream) {
    const float* x     = (const float*)d_in[0];
    const float* gamma = (const float*)d_in[1];
    const float* beta  = (const float*)d_in[2];
    const float* Wq    = (const float*)d_in[3];
    const float* bq    = (const float*)d_in[4];
    const float* Wk    = (const float*)d_in[5];
    const float* bk    = (const float*)d_in[6];
    const float* Wv    = (const float*)d_in[7];
    const float* bv    = (const float*)d_in[8];
    const float* Wo    = (const float*)d_in[9];
    const float* bo    = (const float*)d_in[10];
    float* out = (float*)d_out;

    // B=4, N=4096, C=512, G=32 — ws layout
    char* ws = (char*)d_ws;
    float* stats  = (float*)(ws);                        // 128*2 f32
    float* bqkv   = (float*)(ws + 4096);                 // 1536 f32
    u16*   wqkv_t = (u16*)(ws + 16384);                  // [1536,512]
    u16*   wo_t   = wqkv_t + (size_t)1536 * 512;
    u16*   h      = wo_t + (size_t)512 * 512;            // [16384,512] (aliased as ao)
    u16*   qkv    = h   + (size_t)16384 * 512;           // [16384,1536]
    u16*   vt     = qkv + (size_t)16384 * 1536;          // [4][512][4096]
    u16*   ao     = h;                                   // h dead after QKV GEMM

    const long long sQKV = (long long)4096 * 1536;
    const long long sVT  = (long long)512 * 4096;

    dim3 tblk(32, 8, 1);
    transpose_f2b<<<dim3(16, 16, 1), tblk, 0, stream>>>(Wq, wqkv_t);
    transpose_f2b<<<dim3(16, 16, 1), tblk, 0, stream>>>(Wk, wqkv_t + 512 * 512);
    transpose_f2b<<<dim3(16, 16, 1), tblk, 0, stream>>>(Wv, wqkv_t + 1024 * 512);
    transpose_f2b<<<dim3(16, 16, 1), tblk, 0, stream>>>(Wo, wo_t);
    concat_bias_f<<<6, 256, 0, stream>>>(bq, bk, bv, bqkv);

    gn_stats_k<<<128, 256, 0, stream>>>(x, stats);
    gn_apply_k<<<8192, 256, 0, stream>>>(x, gamma, beta, stats, h);

    // QKV: [16384,512] @ [512,1536] -> qkv (+bias)
    gemm_bt<<<dim3(128, 12, 1), 256, 0, stream>>>(h, 512, wqkv_t, 512,
                                                  qkv, nullptr, 1536, bqkv, nullptr,
                                                  512, 1.0f);
    // v -> vt[b][c][n]
    transpose_b2b<<<dim3(128, 16, 4), tblk, 0, stream>>>(qkv + 1024, vt, 1536, 4096,
                                                         sQKV, sVT);
    // fused attention -> ao (512 blocks, 2 per CU)
    hipFuncSetAttribute((const void*)flash_k,
                        hipFuncAttributeMaxDynamicSharedMemorySize, FLASH_SMEM);
    flash_k<<<dim3(128, 4, 1), 256, FLASH_SMEM, stream>>>(qkv, vt, ao);

    // out = ao @ Wo + bo + x   (fp32 output + bias + residual)
    gemm_bt<<<dim3(128, 4, 1), 256, 0, stream>>>(ao, 512, wo_t, 512,
                                                 nullptr, out, 512, bo, x,
                                                 512, 1.0f);
}